// Round 1
// baseline (386.090 us; speedup 1.0000x reference)
//
#include <hip/hip_runtime.h>
#include <stdint.h>

#define BB 64
#define SS 1024
#define CC 512
#define EPS 1e-5f

typedef __attribute__((ext_vector_type(8))) __bf16 bf16x8;
typedef __attribute__((ext_vector_type(8))) unsigned short ushort8v;
typedef __attribute__((ext_vector_type(4))) float f32x4;

__device__ __forceinline__ unsigned short f2bf(float f) {
    unsigned int u = __builtin_bit_cast(unsigned int, f);
    u += 0x7fffu + ((u >> 16) & 1u);   // round-to-nearest-even
    return (unsigned short)(u >> 16);
}

// ---------------- K0: lin_w fp32 -> bf16 (same [t][s] layout) ----------------
__global__ __launch_bounds__(256) void k_convert_w(const float* __restrict__ w,
                                                   unsigned short* __restrict__ wb) {
    int i = blockIdx.x * 256 + threadIdx.x;   // float4 index, 1024*1024/4 total
    float4 v = ((const float4*)w)[i];
    ushort4 o;
    o.x = f2bf(v.x); o.y = f2bf(v.y); o.z = f2bf(v.z); o.w = f2bf(v.w);
    ((ushort4*)wb)[i] = o;
}

// ---------------- K1a: partial sum/sumsq per (batch, group) ----------------
__global__ __launch_bounds__(256) void k_stats1(const float* __restrict__ x,
                                                float* __restrict__ psum,
                                                float* __restrict__ psq) {
    int b = blockIdx.x >> 5, g = blockIdx.x & 31;        // 32 groups/batch
    const float4* x4 = (const float4*)(x + (size_t)b * SS * CC + (size_t)g * 16384);
    float s = 0.f, q = 0.f;
    int t = threadIdx.x;
#pragma unroll
    for (int i = 0; i < 16; ++i) {
        float4 v = x4[t + i * 256];
        s += v.x + v.y + v.z + v.w;
        q += v.x * v.x + v.y * v.y + v.z * v.z + v.w * v.w;
    }
    for (int off = 32; off; off >>= 1) {
        s += __shfl_down(s, off, 64);
        q += __shfl_down(q, off, 64);
    }
    __shared__ float ls[4], lq[4];
    int w = t >> 6;
    if ((t & 63) == 0) { ls[w] = s; lq[w] = q; }
    __syncthreads();
    if (t == 0) {
        psum[blockIdx.x] = ls[0] + ls[1] + ls[2] + ls[3];
        psq[blockIdx.x]  = lq[0] + lq[1] + lq[2] + lq[3];
    }
}

// ---------------- K1b: finalize mu, rsigma per batch ----------------
__global__ __launch_bounds__(64) void k_stats2(const float* __restrict__ psum,
                                               const float* __restrict__ psq,
                                               float* __restrict__ mu,
                                               float* __restrict__ rsig) {
    int b = blockIdx.x, t = threadIdx.x;
    float s = (t < 32) ? psum[b * 32 + t] : 0.f;
    float q = (t < 32) ? psq[b * 32 + t] : 0.f;
    for (int off = 32; off; off >>= 1) {
        s += __shfl_down(s, off, 64);
        q += __shfl_down(q, off, 64);
    }
    if (t == 0) {
        const float inv = 1.f / (float)(SS * CC);
        float m = s * inv;
        float v = q * inv - m * m;
        mu[b] = m;
        rsig[b] = rsqrtf(v + EPS);
    }
}

// ---------------- K2: h = LN(x) -> bf16, stored transposed Ht[b][c][s] ----------------
// tile 64 s x 64 c, LDS transpose at dword (s-pair) granularity, stride 33 (2-way max)
__global__ __launch_bounds__(256) void k_norm_t(const float* __restrict__ x,
                                                const float* __restrict__ lnw,
                                                const float* __restrict__ lnb,
                                                const float* __restrict__ muA,
                                                const float* __restrict__ rsA,
                                                unsigned short* __restrict__ Ht) {
    int idx = blockIdx.x;
    int b = idx >> 7;                  // 128 tiles per batch (16 s-tiles * 8 c-tiles)
    int rem = idx & 127;
    int s0 = (rem >> 3) << 6;
    int c0 = (rem & 7) << 6;
    float mu = muA[b], rs = rsA[b];
    __shared__ uint32_t lds[64 * 33];
    int t = threadIdx.x;
    int cq = t & 15, spA = t >> 4;
#pragma unroll
    for (int h = 0; h < 2; ++h) {
        int sp = spA + h * 16;                 // s-pair index 0..31
        int sl = s0 + 2 * sp;
        int cc = c0 + 4 * cq;
        size_t xb = ((size_t)b * SS + sl) * CC + cc;
        size_t lb = (size_t)sl * CC + cc;
        float4 xv0 = *(const float4*)(x + xb);
        float4 xv1 = *(const float4*)(x + xb + CC);
        float4 wv0 = *(const float4*)(lnw + lb);
        float4 wv1 = *(const float4*)(lnw + lb + CC);
        float4 bv0 = *(const float4*)(lnb + lb);
        float4 bv1 = *(const float4*)(lnb + lb + CC);
        uint32_t u0 = (uint32_t)f2bf((xv0.x - mu) * rs * wv0.x + bv0.x) |
                      ((uint32_t)f2bf((xv1.x - mu) * rs * wv1.x + bv1.x) << 16);
        uint32_t u1 = (uint32_t)f2bf((xv0.y - mu) * rs * wv0.y + bv0.y) |
                      ((uint32_t)f2bf((xv1.y - mu) * rs * wv1.y + bv1.y) << 16);
        uint32_t u2 = (uint32_t)f2bf((xv0.z - mu) * rs * wv0.z + bv0.z) |
                      ((uint32_t)f2bf((xv1.z - mu) * rs * wv1.z + bv1.z) << 16);
        uint32_t u3 = (uint32_t)f2bf((xv0.w - mu) * rs * wv0.w + bv0.w) |
                      ((uint32_t)f2bf((xv1.w - mu) * rs * wv1.w + bv1.w) << 16);
        lds[(4 * cq + 0) * 33 + sp] = u0;
        lds[(4 * cq + 1) * 33 + sp] = u1;
        lds[(4 * cq + 2) * 33 + sp] = u2;
        lds[(4 * cq + 3) * 33 + sp] = u3;
    }
    __syncthreads();
    int spq = t & 7, clA = t >> 3;
#pragma unroll
    for (int h = 0; h < 2; ++h) {
        int cl = clA + h * 32;
        uint4 v;
        v.x = lds[cl * 33 + spq * 4 + 0];
        v.y = lds[cl * 33 + spq * 4 + 1];
        v.z = lds[cl * 33 + spq * 4 + 2];
        v.w = lds[cl * 33 + spq * 4 + 3];
        size_t o = (((size_t)b * CC + c0 + cl) * SS + (size_t)s0 + spq * 8) >> 3;
        ((uint4*)Ht)[o] = v;
    }
}

// ---------------- K3: batched GEMM (m97 structure) + fused epilogue ----------------
// A = Wbf16 [M=1024][K=1024], B = Ht[b] [N=512][K=1024] (N-major, K contiguous)
// out[b][t][c] = x[b][t][c] + relu(acc[t][c] + lin_b[t])
__global__ __launch_bounds__(256) void k_gemm(const unsigned short* __restrict__ A,
                                              const unsigned short* __restrict__ Bt,
                                              const float* __restrict__ x,
                                              const float* __restrict__ linb,
                                              float* __restrict__ out) {
    const int b = blockIdx.z;
    const int tm = blockIdx.y;   // 0..7
    const int tn = blockIdx.x;   // 0..3
    __shared__ __align__(16) unsigned short As[128 * 32];
    __shared__ __align__(16) unsigned short Bs[128 * 32];
    const int tid = threadIdx.x;
    const int lane = tid & 63;
    const int w = tid >> 6;
    const int wm = w >> 1, wn = w & 1;
    const int quad = lane >> 4, l15 = lane & 15;

    f32x4 acc[4][4];
#pragma unroll
    for (int mi = 0; mi < 4; ++mi)
#pragma unroll
        for (int ni = 0; ni < 4; ++ni)
            acc[mi][ni] = (f32x4){0.f, 0.f, 0.f, 0.f};

    const unsigned short* Ab = A + (size_t)(tm * 128) * 1024;
    const unsigned short* Bb = Bt + ((size_t)b * 512 + tn * 128) * 1024;
    const int srow = tid >> 2;        // 0..63
    const int scol = (tid & 3) * 8;   // bf16 k-offset within row

    for (int k0 = 0; k0 < 1024; k0 += 32) {
        __syncthreads();
#pragma unroll
        for (int q = 0; q < 2; ++q) {
            const unsigned short* ga = Ab + (size_t)(q * 64 + srow) * 1024 + k0 + scol;
            const unsigned short* gb = Bb + (size_t)(q * 64 + srow) * 1024 + k0 + scol;
            __builtin_amdgcn_global_load_lds(
                (const __attribute__((address_space(1))) void*)ga,
                (__attribute__((address_space(3))) void*)(As + q * 2048 + w * 512),
                16, 0, 0);
            __builtin_amdgcn_global_load_lds(
                (const __attribute__((address_space(1))) void*)gb,
                (__attribute__((address_space(3))) void*)(Bs + q * 2048 + w * 512),
                16, 0, 0);
        }
        __syncthreads();

        bf16x8 av[4], bv[4];
#pragma unroll
        for (int i = 0; i < 4; ++i) {
            ushort8v a = *(const ushort8v*)&As[(wm * 64 + i * 16 + l15) * 32 + quad * 8];
            ushort8v bfr = *(const ushort8v*)&Bs[(wn * 64 + i * 16 + l15) * 32 + quad * 8];
            av[i] = __builtin_bit_cast(bf16x8, a);
            bv[i] = __builtin_bit_cast(bf16x8, bfr);
        }
#pragma unroll
        for (int mi = 0; mi < 4; ++mi)
#pragma unroll
            for (int ni = 0; ni < 4; ++ni)
                acc[mi][ni] = __builtin_amdgcn_mfma_f32_16x16x32_bf16(
                    av[mi], bv[ni], acc[mi][ni], 0, 0, 0);
    }

    // epilogue: C/D layout col=lane&15, row=quad*4+reg  [m89/m91 verified]
#pragma unroll
    for (int mi = 0; mi < 4; ++mi) {
#pragma unroll
        for (int r = 0; r < 4; ++r) {
            int tt = tm * 128 + wm * 64 + mi * 16 + quad * 4 + r;
            float lb = linb[tt];
#pragma unroll
            for (int ni = 0; ni < 4; ++ni) {
                int cc = tn * 128 + wn * 64 + ni * 16 + l15;
                size_t o = ((size_t)b * SS + tt) * CC + cc;
                float v = acc[mi][ni][r] + lb;
                v = v > 0.f ? v : 0.f;
                out[o] = x[o] + v;
            }
        }
    }
}

extern "C" void kernel_launch(void* const* d_in, const int* in_sizes, int n_in,
                              void* d_out, int out_size, void* d_ws, size_t ws_size,
                              hipStream_t stream) {
    (void)in_sizes; (void)n_in; (void)out_size; (void)ws_size;
    const float* x    = (const float*)d_in[0];
    const float* lnw  = (const float*)d_in[1];
    const float* lnb  = (const float*)d_in[2];
    const float* linw = (const float*)d_in[3];
    const float* linb = (const float*)d_in[4];
    float* out = (float*)d_out;

    char* ws = (char*)d_ws;
    unsigned short* Wb = (unsigned short*)ws;                       // 2 MB
    unsigned short* Ht = (unsigned short*)(ws + (2u << 20));        // 64 MB
    float* psum = (float*)(ws + (66u << 20));                       // 8 KB
    float* psq  = psum + 2048;
    float* mu   = psq + 2048;
    float* rsig = mu + 64;

    k_convert_w<<<1024, 256, 0, stream>>>(linw, Wb);
    k_stats1<<<2048, 256, 0, stream>>>(x, psum, psq);
    k_stats2<<<64, 64, 0, stream>>>(psum, psq, mu, rsig);
    k_norm_t<<<8192, 256, 0, stream>>>(x, lnw, lnb, mu, rsig, Ht);
    dim3 g(4, 8, 64);
    k_gemm<<<g, 256, 0, stream>>>(Wb, Ht, x, linb, out);
}